// Round 9
// baseline (375.709 us; speedup 1.0000x reference)
//
#include <hip/hip_runtime.h>
#include <hip/hip_fp16.h>

#define NN 50000
#define EE 800000
#define NBUCK 196   // dst buckets of 256 nodes each
#define CAP 5120    // per-bucket edge capacity (mean ~4082, sigma ~64 -> 16 sigma)
#define TILEA 2048
#define NBA ((EE + TILEA - 1) / TILEA)   // 391
#define NGB 782     // ceil(50000/64) row blocks for MFMA gemm1
#define SRCS_MAX (EE + 8 * NN + 64)      // padded CSR upper bound + slack
#define LOG2E 1.4426950408889634f

typedef _Float16 half8 __attribute__((ext_vector_type(8)));
typedef float floatx4 __attribute__((ext_vector_type(4)));
typedef float floatx2 __attribute__((ext_vector_type(2)));

// fp8 e4m3 (OCP) helpers — gfx950 native converts
__device__ __forceinline__ unsigned char f32_to_fp8(float a) {
    int r = __builtin_amdgcn_cvt_pk_fp8_f32(a, a, 0, false);
    return (unsigned char)(r & 0xff);
}
__device__ __forceinline__ float2 fp8pair_lo(unsigned v) {
    floatx2 r = __builtin_amdgcn_cvt_pk_f32_fp8(v, false);
    return make_float2(r[0], r[1]);
}
__device__ __forceinline__ float2 fp8pair_hi(unsigned v) {
    floatx2 r = __builtin_amdgcn_cvt_pk_f32_fp8(v, true);
    return make_float2(r[0], r[1]);
}
// opaque 0: defeats LICM/CSE across rep iterations (measurement only)
__device__ __forceinline__ int opaque_zero() {
    int z = 0;
    asm volatile("" : "+v"(z));
    return z;
}
// ---- native transcendentals -----------------------------------------------------
__device__ __forceinline__ float fexp2(float x) {       // input pre-scaled by log2e
#if __has_builtin(__builtin_amdgcn_exp2f)
    return __builtin_amdgcn_exp2f(x);
#else
    return exp2f(x);
#endif
}
__device__ __forceinline__ float fexp(float x) {
    return fexp2(x * LOG2E);
}
__device__ __forceinline__ float flog(float x) {
#if __has_builtin(__builtin_amdgcn_logf)
    return 0.6931471805599453f * __builtin_amdgcn_logf(x);
#else
    return __logf(x);
#endif
}
__device__ __forceinline__ float frcp(float x) {
#if __has_builtin(__builtin_amdgcn_rcpf)
    return __builtin_amdgcn_rcpf(x);
#else
    return 1.f / x;
#endif
}

// ---------- prep: W1/W2 -> fp16 MFMA B-fragments; cursor; sentinel rows ---------
__global__ void k_prep(const float* __restrict__ W1, const float* __restrict__ W2,
                       _Float16* __restrict__ Bf1, _Float16* __restrict__ Bf2,
                       int* __restrict__ cursor, float* __restrict__ alsrc,
                       float* __restrict__ al2s, unsigned char* __restrict__ h1,
                       __half* __restrict__ h2p) {
    int tid = blockIdx.x * 256 + threadIdx.x;
    if (tid < 1024) {
        int kk = tid >> 8, ct = (tid >> 6) & 3, L = tid & 63;
        int k0 = kk * 32 + (L >> 4) * 8, col = ct * 16 + (L & 15);
        half8 v;
        #pragma unroll
        for (int j = 0; j < 8; j++) v[j] = (_Float16)W1[(k0 + j) * 64 + col];
        *(half8*)(Bf1 + ((size_t)((kk * 4 + ct) * 64 + L)) * 8) = v;
    } else if (tid < 1024 + 384) {
        int u = tid - 1024;
        int kk = u / 192, rem = u % 192;
        int ct = rem >> 6, L = rem & 63;
        int k0 = kk * 32 + (L >> 4) * 8, col = ct * 16 + (L & 15);
        half8 v;
        #pragma unroll
        for (int j = 0; j < 8; j++)
            v[j] = (col < 40) ? (_Float16)W2[(k0 + j) * 40 + col] : (_Float16)0.f;
        *(half8*)(Bf2 + ((size_t)((kk * 3 + ct) * 64 + L)) * 8) = v;
    } else {
        int u = tid - 1408;
        if (u < NBUCK) cursor[u] = 0;
        if (u >= 200 && u < 208) alsrc[(size_t)NN * 8 + (u - 200)] = -1e30f;
        if (u == 208) al2s[NN] = -1e30f;
        if (u >= 224 && u < 240) ((unsigned*)(h1 + (size_t)NN * 64))[u - 224] = 0u;
        if (u >= 240 && u < 260) ((unsigned*)(h2p + (size_t)NN * 40))[u - 240] = 0u;
    }
}

// ---------- FUSED independent stage: blocks [0,NBA) bucketA, [NBA,NBA+NGB) gemm1
__global__ __launch_bounds__(256) void k_fusedAG(
    const int* __restrict__ ei, int* __restrict__ cursor,
    unsigned* __restrict__ bucketData,
    const float* __restrict__ x, const float* __restrict__ topo,
    const _Float16* __restrict__ Bf1,
    const float* __restrict__ a_src, const float* __restrict__ a_dst,
    unsigned char* __restrict__ h1, float* __restrict__ alsrc, float* __restrict__ aldst) {
    if (blockIdx.x < NBA) {
        __shared__ int cnt[NBUCK], base[NBUCK];
        int t = threadIdx.x;
        for (int i = t; i < NBUCK; i += 256) cnt[i] = 0;
        __syncthreads();
        int e0 = blockIdx.x * TILEA;
        int nE = min(TILEA, EE - e0);
        unsigned pk[8]; int bk[8], rk[8];
        int m = 0;
        for (int i = t; i < nE; i += 256) {
            int e = e0 + i;
            int s = ei[e], d = ei[EE + e];
            pk[m] = ((unsigned)d << 16) | (unsigned)s;
            bk[m] = d >> 8;
            rk[m] = atomicAdd(&cnt[bk[m]], 1);
            m++;
        }
        __syncthreads();
        for (int i = t; i < NBUCK; i += 256)
            base[i] = (cnt[i] > 0) ? atomicAdd(&cursor[i], cnt[i]) : 0;
        __syncthreads();
        for (int k = 0; k < m; k++) {
            int pos = base[bk[k]] + rk[k];
            if (pos < CAP) bucketData[(size_t)bk[k] * CAP + pos] = pk[k];
        }
        return;
    }
    // ---- gemm1: MFMA h1(fp8 e4m3) = [x|topo] @ W1 + attention logits (fp32)
    int wave = threadIdx.x >> 6, lane = threadIdx.x & 63;
    int row0 = (blockIdx.x - NBA) * 64 + wave * 16;
    if (row0 >= NN) return;
    int g = lane >> 4, li = lane & 15;
    int myrow = row0 + li;                        // A-operand row (m = lane&15)
    half8 B[16];
    const half8* bp = (const half8*)Bf1;
    #pragma unroll
    for (int i = 0; i < 16; i++) B[i] = bp[i * 64 + lane];
    floatx4 acc[4] = {{0,0,0,0},{0,0,0,0},{0,0,0,0},{0,0,0,0}};
    #pragma unroll
    for (int kk = 0; kk < 4; kk++) {
        int k0 = kk * 32 + g * 8;
        const float* sp = (k0 == 120) ? (topo + (size_t)myrow * 8)
                                      : (x + (size_t)myrow * 120 + k0);
        float4 u0 = ((const float4*)sp)[0];
        float4 u1 = ((const float4*)sp)[1];
        half8 av;
        av[0] = (_Float16)u0.x; av[1] = (_Float16)u0.y;
        av[2] = (_Float16)u0.z; av[3] = (_Float16)u0.w;
        av[4] = (_Float16)u1.x; av[5] = (_Float16)u1.y;
        av[6] = (_Float16)u1.z; av[7] = (_Float16)u1.w;
        #pragma unroll
        for (int ct = 0; ct < 4; ct++)
            acc[ct] = __builtin_amdgcn_mfma_f32_16x16x32_f16(av, B[kk * 4 + ct], acc[ct], 0, 0, 0);
    }
    // C layout: col = ct*16+li, row = row0 + 4*g + r
    #pragma unroll
    for (int ct = 0; ct < 4; ct++)
        #pragma unroll
        for (int r = 0; r < 4; r++)
            h1[(size_t)(row0 + 4 * g + r) * 64 + ct * 16 + li] = f32_to_fp8(acc[ct][r]);
    // attention logits: head = 2*ct + (li>>3), dim = li&7 (heads are 8-col aligned)
    float ps[4][4], pd[4][4];
    #pragma unroll
    for (int ct = 0; ct < 4; ct++) {
        int head = 2 * ct + (li >> 3), dix = li & 7;
        float asv = a_src[head * 8 + dix];
        float adv = a_dst[head * 8 + dix];
        #pragma unroll
        for (int r = 0; r < 4; r++) {
            ps[ct][r] = acc[ct][r] * asv;
            pd[ct][r] = acc[ct][r] * adv;
        }
    }
    #pragma unroll
    for (int off = 1; off <= 4; off <<= 1)
        #pragma unroll
        for (int ct = 0; ct < 4; ct++)
            #pragma unroll
            for (int r = 0; r < 4; r++) {
                ps[ct][r] += __shfl_xor(ps[ct][r], off, 64);
                pd[ct][r] += __shfl_xor(pd[ct][r], off, 64);
            }
    if ((li & 7) == 0) {
        #pragma unroll
        for (int ct = 0; ct < 4; ct++) {
            int head = 2 * ct + (li >> 3);
            #pragma unroll
            for (int r = 0; r < 4; r++) {
                int row = row0 + 4 * g + r;
                alsrc[row * 8 + head] = ps[ct][r] * LOG2E;   // pre-scaled for exp2
                aldst[row * 8 + head] = pd[ct][r] * LOG2E;
            }
        }
    }
}

// ---------- Pass B (1024 threads): inline arena scan + per-bucket counting sort -
__global__ __launch_bounds__(1024) void k_bucketB(const unsigned* __restrict__ bucketData,
        const int* __restrict__ cursor,
        int2* __restrict__ rowseg, int* __restrict__ srcs) {
    __shared__ int cnt[256], cur[256], sbuf[256], svals[256];
    __shared__ int sorted[CAP + 2048];
    int b = blockIdx.x, t = threadIdx.x;
    int nloc = min(256, NN - b * 256);
    int ecnt = min(cursor[b], CAP);
    size_t inBase = (size_t)b * CAP;
    if (t < 256) {
        int vv = 0;
        if (t < NBUCK) {
            int nl = min(256, NN - t * 256);
            vv = min(cursor[t], CAP) + 8 * nl;
        }
        svals[t] = vv;
    }
    __syncthreads();
    int* a = svals; int* bb = sbuf;
    for (int off = 1; off < 256; off <<= 1) {
        if (t < 256) bb[t] = a[t] + ((t >= off) ? a[t - off] : 0);
        __syncthreads();
        int* tmp = a; a = bb; bb = tmp;
    }
    int outBase = (b == 0) ? 0 : a[b - 1];
    __syncthreads();
    if (t < 256) cnt[t] = (t < nloc) ? 1 : 0;
    __syncthreads();
    for (int i = t; i < ecnt; i += 1024) {
        unsigned u = bucketData[inBase + i];
        atomicAdd(&cnt[(u >> 16) & 255], 1);
    }
    __syncthreads();
    int cv = 0, pcv = 0;
    if (t < 256) {
        cv = cnt[t];
        pcv = (t < nloc) ? ((cv + 7) & ~7) : 0;
        sbuf[t] = pcv;
    }
    __syncthreads();
    a = sbuf; bb = cnt;
    for (int off = 1; off < 256; off <<= 1) {
        if (t < 256) bb[t] = a[t] + ((t >= off) ? a[t - off] : 0);
        __syncthreads();
        int* tmp = a; a = bb; bb = tmp;
    }
    int total = a[255];
    int excl = (t < 256) ? (a[t] - pcv) : 0;
    __syncthreads();
    if (t < nloc) {
        rowseg[b * 256 + t] = make_int2(outBase + excl, outBase + excl + pcv);
        sorted[excl] = b * 256 + t;              // self loop at slot 0 of segment
        for (int k = cv; k < pcv; k++) sorted[excl + k] = NN;  // sentinel pads
        cur[t] = excl + 1;
    }
    __syncthreads();
    for (int i = t; i < ecnt; i += 1024) {
        unsigned u = bucketData[inBase + i];
        int ld = (u >> 16) & 255;
        int p = atomicAdd(&cur[ld], 1);
        sorted[p] = (int)(u & 0xffffu);
    }
    __syncthreads();
    for (int i = t; i < total; i += 1024) srcs[outBase + i] = sorted[i];
}

// ------- layer 1 aggregation: 1 edge/lane, 8 cols/lane, byte-offset addressing --
__global__ __launch_bounds__(256) void k_agg1(
    const int2* __restrict__ rowseg, const int* __restrict__ srcs,
    const float* __restrict__ alsrc, const float* __restrict__ aldst,
    const unsigned char* __restrict__ h1, const float* __restrict__ b1,
    __half* __restrict__ hout, int reps) {
    int wave = threadIdx.x >> 6;
    int lane = threadIdx.x & 63;
    int d = blockIdx.x * 4 + wave;
    if (d >= NN) return;
    int eh = lane >> 3;          // edge slot 0..7
    int cq = lane & 7;           // head / col-octet
    unsigned cq4 = (unsigned)cq << 2, cq8 = (unsigned)cq << 3;
    for (int rep = 0; rep < reps; rep++) {
        int oz = opaque_zero();
        const int* S = srcs + oz;
        const char* AL = (const char*)(alsrc + oz);
        const char* H = (const char*)(h1 + oz);
        float adst = aldst[d * 8 + cq];
        int2 seg = rowseg[d];
        int jb = seg.x, je = seg.y;
        int s = S[jb + eh];
        float al = *(const float*)(AL + (((unsigned)s << 5) | cq4));
        uint2 q = *(const uint2*)(H + (((unsigned)s << 6) | cq8));
        float c0 = 0.f, c1 = 0.f, c2 = 0.f, c3 = 0.f;
        float c4 = 0.f, c5 = 0.f, c6 = 0.f, c7 = 0.f, ssum = 0.f;
        for (int j = jb; j < je; j += 8) {
            int jn = min(j + 8, je - 8);       // wave-uniform, always in-arena
            int sn = S[jn + eh];
            float aln = *(const float*)(AL + (((unsigned)sn << 5) | cq4));
            uint2 qn = *(const uint2*)(H + (((unsigned)sn << 6) | cq8));
            float e = al + adst;               // pre-scaled by log2e
            float p = fexp2(fmaxf(e, 0.2f * e));
            float2 f0 = fp8pair_lo(q.x), f1 = fp8pair_hi(q.x);
            float2 f2 = fp8pair_lo(q.y), f3 = fp8pair_hi(q.y);
            ssum += p;
            c0 += p * f0.x; c1 += p * f0.y;
            c2 += p * f1.x; c3 += p * f1.y;
            c4 += p * f2.x; c5 += p * f2.y;
            c6 += p * f3.x; c7 += p * f3.y;
            al = aln; q = qn;
        }
        #pragma unroll
        for (int off = 8; off <= 32; off <<= 1) {
            ssum += __shfl_xor(ssum, off, 64);
            c0 += __shfl_xor(c0, off, 64); c1 += __shfl_xor(c1, off, 64);
            c2 += __shfl_xor(c2, off, 64); c3 += __shfl_xor(c3, off, 64);
            c4 += __shfl_xor(c4, off, 64); c5 += __shfl_xor(c5, off, 64);
            c6 += __shfl_xor(c6, off, 64); c7 += __shfl_xor(c7, off, 64);
        }
        if (eh == 0) {
            float4 bl = ((const float4*)b1)[2 * cq];
            float4 bh = ((const float4*)b1)[2 * cq + 1];
            float inv = frcp(ssum);
            float v0 = c0 * inv + bl.x, v1 = c1 * inv + bl.y;
            float v2 = c2 * inv + bl.z, v3 = c3 * inv + bl.w;
            float v4 = c4 * inv + bh.x, v5 = c5 * inv + bh.y;
            float v6 = c6 * inv + bh.z, v7 = c7 * inv + bh.w;
            v0 = (v0 > 0.f) ? v0 : (fexp(v0) - 1.f);   // ELU
            v1 = (v1 > 0.f) ? v1 : (fexp(v1) - 1.f);
            v2 = (v2 > 0.f) ? v2 : (fexp(v2) - 1.f);
            v3 = (v3 > 0.f) ? v3 : (fexp(v3) - 1.f);
            v4 = (v4 > 0.f) ? v4 : (fexp(v4) - 1.f);
            v5 = (v5 > 0.f) ? v5 : (fexp(v5) - 1.f);
            v6 = (v6 > 0.f) ? v6 : (fexp(v6) - 1.f);
            v7 = (v7 > 0.f) ? v7 : (fexp(v7) - 1.f);
            __half2 p0 = __floats2half2_rn(v0, v1);
            __half2 p1 = __floats2half2_rn(v2, v3);
            __half2 p2 = __floats2half2_rn(v4, v5);
            __half2 p3 = __floats2half2_rn(v6, v7);
            uint4 pk;
            pk.x = *(unsigned*)&p0; pk.y = *(unsigned*)&p1;
            pk.z = *(unsigned*)&p2; pk.w = *(unsigned*)&p3;
            *(uint4*)(hout + (size_t)d * 64 + 8 * cq) = pk;
        }
    }
}

// ------- layer 2 node GEMM via MFMA (h2p fp16, PACKED 40-col/80B rows) ----------
__global__ __launch_bounds__(256) void k_gemm2(
    const __half* __restrict__ hout, const _Float16* __restrict__ Bf2,
    const float* __restrict__ a_src2, const float* __restrict__ a_dst2,
    __half* __restrict__ h2p, float* __restrict__ al2s, float* __restrict__ al2d) {
    int wave = threadIdx.x >> 6, lane = threadIdx.x & 63;
    int row0 = blockIdx.x * 64 + wave * 16;
    if (row0 >= NN) return;
    int g = lane >> 4, li = lane & 15;
    int myrow = row0 + li;
    half8 B[6];
    const half8* bp = (const half8*)Bf2;
    #pragma unroll
    for (int i = 0; i < 6; i++) B[i] = bp[i * 64 + lane];
    floatx4 acc[3] = {{0,0,0,0},{0,0,0,0},{0,0,0,0}};
    #pragma unroll
    for (int kk = 0; kk < 2; kk++) {
        int k0 = kk * 32 + g * 8;
        half8 av = *(const half8*)(hout + (size_t)myrow * 64 + k0);
        #pragma unroll
        for (int ct = 0; ct < 3; ct++)
            acc[ct] = __builtin_amdgcn_mfma_f32_16x16x32_f16(av, B[kk * 3 + ct], acc[ct], 0, 0, 0);
    }
    float ts[4] = {0.f, 0.f, 0.f, 0.f}, td[4] = {0.f, 0.f, 0.f, 0.f};
    #pragma unroll
    for (int ct = 0; ct < 3; ct++) {
        int col = ct * 16 + li;
        bool ok = (col < 40);
        float asv = ok ? a_src2[col] : 0.f;
        float adv = ok ? a_dst2[col] : 0.f;
        #pragma unroll
        for (int r = 0; r < 4; r++) {
            ts[r] += acc[ct][r] * asv;
            td[r] += acc[ct][r] * adv;
            if (ok) h2p[(size_t)(row0 + 4 * g + r) * 40 + col] = __float2half(acc[ct][r]);
        }
    }
    #pragma unroll
    for (int off = 1; off <= 8; off <<= 1)
        #pragma unroll
        for (int r = 0; r < 4; r++) {
            ts[r] += __shfl_xor(ts[r], off, 64);
            td[r] += __shfl_xor(td[r], off, 64);
        }
    if (li == 0) {
        #pragma unroll
        for (int r = 0; r < 4; r++) {
            int row = row0 + 4 * g + r;
            al2s[row] = ts[r] * LOG2E;   // pre-scaled for exp2
            al2d[row] = td[r] * LOG2E;
        }
    }
}

// ------- layer 2 aggregation + log_softmax: 1 edge/lane, packed-80B h2 ----------
__global__ __launch_bounds__(256) void k_agg2(
    const int2* __restrict__ rowseg, const int* __restrict__ srcs,
    const float* __restrict__ al2s, const float* __restrict__ al2d,
    const __half* __restrict__ h2p, const float* __restrict__ b2,
    float* __restrict__ out, int reps) {
    int wave = threadIdx.x >> 6;
    int lane = threadIdx.x & 63;
    int d = blockIdx.x * 4 + wave;
    if (d >= NN) return;
    int eh = lane >> 3;          // edge slot 0..7
    int cq = lane & 7;           // col-octet: cols 8cq..8cq+7; valid iff cq<5
    bool act = (cq < 5);
    int cqc = act ? cq : 4;      // clamped for in-bounds loads (cq>=5 lanes unused)
    unsigned cq16 = (unsigned)cqc << 4;
    for (int rep = 0; rep < reps; rep++) {
        int oz = opaque_zero();
        const int* S = srcs + oz;
        const float* AL = al2s + oz;
        const char* H = (const char*)(h2p + oz);
        float adst = al2d[d];
        int2 seg = rowseg[d];
        int jb = seg.x, je = seg.y;
        int s = S[jb + eh];
        float al = AL[s];
        uint4 q = *(const uint4*)(H + ((unsigned)s * 80u + cq16));
        float c0 = 0.f, c1 = 0.f, c2 = 0.f, c3 = 0.f;
        float c4 = 0.f, c5 = 0.f, c6 = 0.f, c7 = 0.f, ssum = 0.f;
        for (int j = jb; j < je; j += 8) {
            int jn = min(j + 8, je - 8);
            int sn = S[jn + eh];
            float aln = AL[sn];
            uint4 qn = *(const uint4*)(H + ((unsigned)sn * 80u + cq16));
            float e = al + adst;               // pre-scaled by log2e
            float p = fexp2(fmaxf(e, 0.2f * e));
            float2 f0 = __half22float2(*(__half2*)&q.x);
            float2 f1 = __half22float2(*(__half2*)&q.y);
            float2 f2 = __half22float2(*(__half2*)&q.z);
            float2 f3 = __half22float2(*(__half2*)&q.w);
            ssum += p;
            c0 += p * f0.x; c1 += p * f0.y;
            c2 += p * f1.x; c3 += p * f1.y;
            c4 += p * f2.x; c5 += p * f2.y;
            c6 += p * f3.x; c7 += p * f3.y;
            al = aln; q = qn;
        }
        #pragma unroll
        for (int off = 8; off <= 32; off <<= 1) {
            ssum += __shfl_xor(ssum, off, 64);
            c0 += __shfl_xor(c0, off, 64); c1 += __shfl_xor(c1, off, 64);
            c2 += __shfl_xor(c2, off, 64); c3 += __shfl_xor(c3, off, 64);
            c4 += __shfl_xor(c4, off, 64); c5 += __shfl_xor(c5, off, 64);
            c6 += __shfl_xor(c6, off, 64); c7 += __shfl_xor(c7, off, 64);
        }
        float inv = frcp(ssum);
        float4 bl = ((const float4*)b2)[2 * cqc];
        float4 bh = ((const float4*)b2)[2 * cqc + 1];
        float o0 = c0 * inv + bl.x, o1 = c1 * inv + bl.y;
        float o2 = c2 * inv + bl.z, o3 = c3 * inv + bl.w;
        float o4 = c4 * inv + bh.x, o5 = c5 * inv + bh.y;
        float o6 = c6 * inv + bh.z, o7 = c7 * inv + bh.w;
        float mo = act ? fmaxf(fmaxf(fmaxf(o0, o1), fmaxf(o2, o3)),
                               fmaxf(fmaxf(o4, o5), fmaxf(o6, o7))) : -3.0e38f;
        #pragma unroll
        for (int off = 1; off <= 4; off <<= 1) mo = fmaxf(mo, __shfl_xor(mo, off, 64));
        float te = act ? (fexp(o0 - mo) + fexp(o1 - mo) + fexp(o2 - mo) + fexp(o3 - mo) +
                          fexp(o4 - mo) + fexp(o5 - mo) + fexp(o6 - mo) + fexp(o7 - mo)) : 0.f;
        #pragma unroll
        for (int off = 1; off <= 4; off <<= 1) te += __shfl_xor(te, off, 64);
        float ls = mo + flog(te);
        if (act && eh == 0) {
            float4 lo = make_float4(o0 - ls, o1 - ls, o2 - ls, o3 - ls);
            float4 hi = make_float4(o4 - ls, o5 - ls, o6 - ls, o7 - ls);
            *(float4*)(out + (size_t)d * 40 + 8 * cq) = lo;
            *(float4*)(out + (size_t)d * 40 + 8 * cq + 4) = hi;
        }
    }
}

extern "C" void kernel_launch(void* const* d_in, const int* in_sizes, int n_in,
                              void* d_out, int out_size, void* d_ws, size_t ws_size,
                              hipStream_t stream) {
    (void)in_sizes; (void)n_in; (void)out_size; (void)ws_size;
    const float* x    = (const float*)d_in[0];
    const float* topo = (const float*)d_in[1];
    const int*   ei   = (const int*)d_in[2];
    const float* W1   = (const float*)d_in[3];
    const float* as1  = (const float*)d_in[4];
    const float* ad1  = (const float*)d_in[5];
    const float* b1   = (const float*)d_in[6];
    const float* W2   = (const float*)d_in[7];
    const float* as2  = (const float*)d_in[8];
    const float* ad2  = (const float*)d_in[9];
    const float* b2   = (const float*)d_in[10];
    float* out = (float*)d_out;

    char* ws = (char*)d_ws;
    size_t off = 0;
    auto alloc = [&](size_t bytes) {
        void* p = ws + off;
        off += (bytes + 255) / 256 * 256;
        return p;
    };
    int2*          rowseg     = (int2*)alloc((size_t)NN * 8);
    int*           cursor     = (int*)alloc(NBUCK * 4);
    unsigned*      bucketData = (unsigned*)alloc((size_t)NBUCK * CAP * 4);
    int*           srcs       = (int*)alloc((size_t)SRCS_MAX * 4);
    float*         alsrc1     = (float*)alloc((size_t)(NN + 1) * 8 * 4);
    float*         aldst1     = (float*)alloc((size_t)NN * 8 * 4);
    float*         al2s       = (float*)alloc((NN + 1) * 4);
    float*         al2d       = (float*)alloc(NN * 4);
    _Float16*      Bf1        = (_Float16*)alloc(4 * 4 * 64 * 8 * 2);
    _Float16*      Bf2        = (_Float16*)alloc(2 * 3 * 64 * 8 * 2);
    unsigned char* h1         = (unsigned char*)alloc((size_t)(NN + 1) * 64);
    __half*        hout       = (__half*)alloc((size_t)NN * 64 * 2);
    __half*        h2p        = (__half*)alloc((size_t)(NN + 1) * 40 * 2);

    k_prep    <<<7,         256,  0, stream>>>(W1, W2, Bf1, Bf2, cursor, alsrc1, al2s, h1, h2p);
    k_fusedAG <<<NBA + NGB, 256,  0, stream>>>(ei, cursor, bucketData,
                                               x, topo, Bf1, as1, ad1, h1, alsrc1, aldst1);
    k_bucketB <<<NBUCK,     1024, 0, stream>>>(bucketData, cursor, rowseg, srcs);
    k_agg1    <<<(NN + 3) / 4, 256, 0, stream>>>(rowseg, srcs, alsrc1, aldst1, h1, b1, hout, 1);
    k_gemm2   <<<782,       256,  0, stream>>>(hout, Bf2, as2, ad2, h2p, al2s, al2d);
    k_agg2    <<<(NN + 3) / 4, 256, 0, stream>>>(rowseg, srcs, al2s, al2d, h2p, b2, out, 1);
    // ---- ATTRIBUTION EXTRAS: amplified idempotent re-runs (per-pass = dur/5).
    // A/B vs R7's 24.3us/pass baseline; removed next round.
    k_agg1    <<<(NN + 3) / 4, 256, 0, stream>>>(rowseg, srcs, alsrc1, aldst1, h1, b1, hout, 5);
    k_agg2    <<<(NN + 3) / 4, 256, 0, stream>>>(rowseg, srcs, al2s, al2d, h2p, b2, out, 5);
}

// Round 10
// 174.623 us; speedup vs baseline: 2.1515x; 2.1515x over previous
//
#include <hip/hip_runtime.h>
#include <hip/hip_fp16.h>

#define NN 50000
#define EE 800000
#define NBUCK 196   // dst buckets of 256 nodes each
#define CAP 5120    // per-bucket edge capacity (mean ~4082, sigma ~64 -> 16 sigma)
#define TILEA 2048
#define NBA ((EE + TILEA - 1) / TILEA)   // 391
#define NGB 782     // ceil(50000/64) row blocks for MFMA gemm1
#define SRCS_MAX (EE + 8 * NN + 64)      // padded CSR upper bound + slack
#define LOG2E 1.4426950408889634f
#define PF 6        // prefetch slots (48 edges; Poisson(16)+1 -> deg>48 is ~8 sigma)

typedef _Float16 half8 __attribute__((ext_vector_type(8)));
typedef float floatx4 __attribute__((ext_vector_type(4)));
typedef float floatx2 __attribute__((ext_vector_type(2)));

// fp8 e4m3 (OCP) helpers — gfx950 native converts
__device__ __forceinline__ unsigned char f32_to_fp8(float a) {
    int r = __builtin_amdgcn_cvt_pk_fp8_f32(a, a, 0, false);
    return (unsigned char)(r & 0xff);
}
__device__ __forceinline__ float2 fp8pair_lo(unsigned v) {
    floatx2 r = __builtin_amdgcn_cvt_pk_f32_fp8(v, false);
    return make_float2(r[0], r[1]);
}
__device__ __forceinline__ float2 fp8pair_hi(unsigned v) {
    floatx2 r = __builtin_amdgcn_cvt_pk_f32_fp8(v, true);
    return make_float2(r[0], r[1]);
}
// ---- native transcendentals -----------------------------------------------------
__device__ __forceinline__ float fexp2(float x) {       // input pre-scaled by log2e
#if __has_builtin(__builtin_amdgcn_exp2f)
    return __builtin_amdgcn_exp2f(x);
#else
    return exp2f(x);
#endif
}
__device__ __forceinline__ float fexp(float x) {
    return fexp2(x * LOG2E);
}
__device__ __forceinline__ float flog(float x) {
#if __has_builtin(__builtin_amdgcn_logf)
    return 0.6931471805599453f * __builtin_amdgcn_logf(x);
#else
    return __logf(x);
#endif
}
__device__ __forceinline__ float frcp(float x) {
#if __has_builtin(__builtin_amdgcn_rcpf)
    return __builtin_amdgcn_rcpf(x);
#else
    return 1.f / x;
#endif
}

// ---------- prep: W1/W2 -> fp16 MFMA B-fragments; cursor; sentinel rows ---------
__global__ void k_prep(const float* __restrict__ W1, const float* __restrict__ W2,
                       _Float16* __restrict__ Bf1, _Float16* __restrict__ Bf2,
                       int* __restrict__ cursor, float* __restrict__ alsrc,
                       float* __restrict__ al2s, unsigned char* __restrict__ h1,
                       __half* __restrict__ h2p) {
    int tid = blockIdx.x * 256 + threadIdx.x;
    if (tid < 1024) {
        int kk = tid >> 8, ct = (tid >> 6) & 3, L = tid & 63;
        int k0 = kk * 32 + (L >> 4) * 8, col = ct * 16 + (L & 15);
        half8 v;
        #pragma unroll
        for (int j = 0; j < 8; j++) v[j] = (_Float16)W1[(k0 + j) * 64 + col];
        *(half8*)(Bf1 + ((size_t)((kk * 4 + ct) * 64 + L)) * 8) = v;
    } else if (tid < 1024 + 384) {
        int u = tid - 1024;
        int kk = u / 192, rem = u % 192;
        int ct = rem >> 6, L = rem & 63;
        int k0 = kk * 32 + (L >> 4) * 8, col = ct * 16 + (L & 15);
        half8 v;
        #pragma unroll
        for (int j = 0; j < 8; j++)
            v[j] = (col < 40) ? (_Float16)W2[(k0 + j) * 40 + col] : (_Float16)0.f;
        *(half8*)(Bf2 + ((size_t)((kk * 3 + ct) * 64 + L)) * 8) = v;
    } else {
        int u = tid - 1408;
        if (u < NBUCK) cursor[u] = 0;
        if (u >= 200 && u < 208) alsrc[(size_t)NN * 8 + (u - 200)] = -1e30f;
        if (u == 208) al2s[NN] = -1e30f;
        if (u >= 224 && u < 240) ((unsigned*)(h1 + (size_t)NN * 64))[u - 224] = 0u;
        if (u >= 240 && u < 260) ((unsigned*)(h2p + (size_t)NN * 40))[u - 240] = 0u;
    }
}

// ---------- FUSED independent stage: blocks [0,NBA) bucketA, [NBA,NBA+NGB) gemm1
__global__ __launch_bounds__(256) void k_fusedAG(
    const int* __restrict__ ei, int* __restrict__ cursor,
    unsigned* __restrict__ bucketData,
    const float* __restrict__ x, const float* __restrict__ topo,
    const _Float16* __restrict__ Bf1,
    const float* __restrict__ a_src, const float* __restrict__ a_dst,
    unsigned char* __restrict__ h1, float* __restrict__ alsrc, float* __restrict__ aldst) {
    if (blockIdx.x < NBA) {
        __shared__ int cnt[NBUCK], base[NBUCK];
        int t = threadIdx.x;
        for (int i = t; i < NBUCK; i += 256) cnt[i] = 0;
        __syncthreads();
        int e0 = blockIdx.x * TILEA;
        int nE = min(TILEA, EE - e0);
        unsigned pk[8]; int bk[8], rk[8];
        int m = 0;
        for (int i = t; i < nE; i += 256) {
            int e = e0 + i;
            int s = ei[e], d = ei[EE + e];
            pk[m] = ((unsigned)d << 16) | (unsigned)s;
            bk[m] = d >> 8;
            rk[m] = atomicAdd(&cnt[bk[m]], 1);
            m++;
        }
        __syncthreads();
        for (int i = t; i < NBUCK; i += 256)
            base[i] = (cnt[i] > 0) ? atomicAdd(&cursor[i], cnt[i]) : 0;
        __syncthreads();
        for (int k = 0; k < m; k++) {
            int pos = base[bk[k]] + rk[k];
            if (pos < CAP) bucketData[(size_t)bk[k] * CAP + pos] = pk[k];
        }
        return;
    }
    // ---- gemm1: MFMA h1(fp8 e4m3) = [x|topo] @ W1 + attention logits (fp32)
    int wave = threadIdx.x >> 6, lane = threadIdx.x & 63;
    int row0 = (blockIdx.x - NBA) * 64 + wave * 16;
    if (row0 >= NN) return;
    int g = lane >> 4, li = lane & 15;
    int myrow = row0 + li;                        // A-operand row (m = lane&15)
    half8 B[16];
    const half8* bp = (const half8*)Bf1;
    #pragma unroll
    for (int i = 0; i < 16; i++) B[i] = bp[i * 64 + lane];
    floatx4 acc[4] = {{0,0,0,0},{0,0,0,0},{0,0,0,0},{0,0,0,0}};
    #pragma unroll
    for (int kk = 0; kk < 4; kk++) {
        int k0 = kk * 32 + g * 8;
        const float* sp = (k0 == 120) ? (topo + (size_t)myrow * 8)
                                      : (x + (size_t)myrow * 120 + k0);
        float4 u0 = ((const float4*)sp)[0];
        float4 u1 = ((const float4*)sp)[1];
        half8 av;
        av[0] = (_Float16)u0.x; av[1] = (_Float16)u0.y;
        av[2] = (_Float16)u0.z; av[3] = (_Float16)u0.w;
        av[4] = (_Float16)u1.x; av[5] = (_Float16)u1.y;
        av[6] = (_Float16)u1.z; av[7] = (_Float16)u1.w;
        #pragma unroll
        for (int ct = 0; ct < 4; ct++)
            acc[ct] = __builtin_amdgcn_mfma_f32_16x16x32_f16(av, B[kk * 4 + ct], acc[ct], 0, 0, 0);
    }
    // C layout: col = ct*16+li, row = row0 + 4*g + r
    #pragma unroll
    for (int ct = 0; ct < 4; ct++)
        #pragma unroll
        for (int r = 0; r < 4; r++)
            h1[(size_t)(row0 + 4 * g + r) * 64 + ct * 16 + li] = f32_to_fp8(acc[ct][r]);
    // attention logits: head = 2*ct + (li>>3), dim = li&7 (heads are 8-col aligned)
    float ps[4][4], pd[4][4];
    #pragma unroll
    for (int ct = 0; ct < 4; ct++) {
        int head = 2 * ct + (li >> 3), dix = li & 7;
        float asv = a_src[head * 8 + dix];
        float adv = a_dst[head * 8 + dix];
        #pragma unroll
        for (int r = 0; r < 4; r++) {
            ps[ct][r] = acc[ct][r] * asv;
            pd[ct][r] = acc[ct][r] * adv;
        }
    }
    #pragma unroll
    for (int off = 1; off <= 4; off <<= 1)
        #pragma unroll
        for (int ct = 0; ct < 4; ct++)
            #pragma unroll
            for (int r = 0; r < 4; r++) {
                ps[ct][r] += __shfl_xor(ps[ct][r], off, 64);
                pd[ct][r] += __shfl_xor(pd[ct][r], off, 64);
            }
    if ((li & 7) == 0) {
        #pragma unroll
        for (int ct = 0; ct < 4; ct++) {
            int head = 2 * ct + (li >> 3);
            #pragma unroll
            for (int r = 0; r < 4; r++) {
                int row = row0 + 4 * g + r;
                alsrc[row * 8 + head] = ps[ct][r] * LOG2E;   // pre-scaled for exp2
                aldst[row * 8 + head] = pd[ct][r] * LOG2E;
            }
        }
    }
}

// ---------- Pass B (1024 threads): inline arena scan + per-bucket counting sort -
__global__ __launch_bounds__(1024) void k_bucketB(const unsigned* __restrict__ bucketData,
        const int* __restrict__ cursor,
        int2* __restrict__ rowseg, int* __restrict__ srcs) {
    __shared__ int cnt[256], cur[256], sbuf[256], svals[256];
    __shared__ int sorted[CAP + 2048];
    int b = blockIdx.x, t = threadIdx.x;
    int nloc = min(256, NN - b * 256);
    int ecnt = min(cursor[b], CAP);
    size_t inBase = (size_t)b * CAP;
    if (t < 256) {
        int vv = 0;
        if (t < NBUCK) {
            int nl = min(256, NN - t * 256);
            vv = min(cursor[t], CAP) + 8 * nl;
        }
        svals[t] = vv;
    }
    __syncthreads();
    int* a = svals; int* bb = sbuf;
    for (int off = 1; off < 256; off <<= 1) {
        if (t < 256) bb[t] = a[t] + ((t >= off) ? a[t - off] : 0);
        __syncthreads();
        int* tmp = a; a = bb; bb = tmp;
    }
    int outBase = (b == 0) ? 0 : a[b - 1];
    __syncthreads();
    if (t < 256) cnt[t] = (t < nloc) ? 1 : 0;
    __syncthreads();
    for (int i = t; i < ecnt; i += 1024) {
        unsigned u = bucketData[inBase + i];
        atomicAdd(&cnt[(u >> 16) & 255], 1);
    }
    __syncthreads();
    int cv = 0, pcv = 0;
    if (t < 256) {
        cv = cnt[t];
        pcv = (t < nloc) ? ((cv + 7) & ~7) : 0;
        sbuf[t] = pcv;
    }
    __syncthreads();
    a = sbuf; bb = cnt;
    for (int off = 1; off < 256; off <<= 1) {
        if (t < 256) bb[t] = a[t] + ((t >= off) ? a[t - off] : 0);
        __syncthreads();
        int* tmp = a; a = bb; bb = tmp;
    }
    int total = a[255];
    int excl = (t < 256) ? (a[t] - pcv) : 0;
    __syncthreads();
    if (t < nloc) {
        rowseg[b * 256 + t] = make_int2(outBase + excl, outBase + excl + pcv);
        sorted[excl] = b * 256 + t;              // self loop at slot 0 of segment
        for (int k = cv; k < pcv; k++) sorted[excl + k] = NN;  // sentinel pads
        cur[t] = excl + 1;
    }
    __syncthreads();
    for (int i = t; i < ecnt; i += 1024) {
        unsigned u = bucketData[inBase + i];
        int ld = (u >> 16) & 255;
        int p = atomicAdd(&cur[ld], 1);
        sorted[p] = (int)(u & 0xffffu);
    }
    __syncthreads();
    for (int i = t; i < total; i += 1024) srcs[outBase + i] = sorted[i];
}

// ------- layer 1 aggregation: 1 edge/lane, 8 cols/lane, 6-slot batch prefetch ---
__global__ __launch_bounds__(256) void k_agg1(
    const int2* __restrict__ rowseg, const int* __restrict__ srcs,
    const float* __restrict__ alsrc, const float* __restrict__ aldst,
    const unsigned char* __restrict__ h1, const float* __restrict__ b1,
    __half* __restrict__ hout) {
    int wave = threadIdx.x >> 6;
    int lane = threadIdx.x & 63;
    int d = blockIdx.x * 4 + wave;
    if (d >= NN) return;
    int eh = lane >> 3;          // edge slot 0..7
    int cq = lane & 7;           // head / col-octet
    unsigned cq4 = (unsigned)cq << 2, cq8 = (unsigned)cq << 3;
    const char* AL = (const char*)alsrc;
    const char* H = (const char*)h1;
    float adst = aldst[d * 8 + cq];
    int2 seg = rowseg[d];
    int jb = seg.x, je = seg.y;
    int niter = (je - jb) >> 3;          // >= 1 always
    // batch prefetch: all indices in parallel, then all values in parallel
    int idx[PF];
    #pragma unroll
    for (int k = 0; k < PF; k++) {
        int jj = min(jb + 8 * k, je - 8);    // clamped, always in-arena
        idx[k] = srcs[jj + eh];
    }
    float alv[PF]; uint2 qv[PF];
    #pragma unroll
    for (int k = 0; k < PF; k++) {
        alv[k] = *(const float*)(AL + (((unsigned)idx[k] << 5) | cq4));
        qv[k]  = *(const uint2*)(H + (((unsigned)idx[k] << 6) | cq8));
    }
    float c0 = 0.f, c1 = 0.f, c2 = 0.f, c3 = 0.f;
    float c4 = 0.f, c5 = 0.f, c6 = 0.f, c7 = 0.f, ssum = 0.f;
    #pragma unroll
    for (int k = 0; k < PF; k++) {
        if (k >= niter) break;               // wave-uniform
        float e = alv[k] + adst;             // pre-scaled by log2e
        float p = fexp2(fmaxf(e, 0.2f * e));
        float2 f0 = fp8pair_lo(qv[k].x), f1 = fp8pair_hi(qv[k].x);
        float2 f2 = fp8pair_lo(qv[k].y), f3 = fp8pair_hi(qv[k].y);
        ssum += p;
        c0 += p * f0.x; c1 += p * f0.y;
        c2 += p * f1.x; c3 += p * f1.y;
        c4 += p * f2.x; c5 += p * f2.y;
        c6 += p * f3.x; c7 += p * f3.y;
    }
    // tail for deg > 8*PF (astronomically rare; correctness only)
    for (int j = jb + 8 * PF; j < je; j += 8) {
        int sn = srcs[j + eh];
        float al = *(const float*)(AL + (((unsigned)sn << 5) | cq4));
        uint2 q = *(const uint2*)(H + (((unsigned)sn << 6) | cq8));
        float e = al + adst;
        float p = fexp2(fmaxf(e, 0.2f * e));
        float2 f0 = fp8pair_lo(q.x), f1 = fp8pair_hi(q.x);
        float2 f2 = fp8pair_lo(q.y), f3 = fp8pair_hi(q.y);
        ssum += p;
        c0 += p * f0.x; c1 += p * f0.y;
        c2 += p * f1.x; c3 += p * f1.y;
        c4 += p * f2.x; c5 += p * f2.y;
        c6 += p * f3.x; c7 += p * f3.y;
    }
    #pragma unroll
    for (int off = 8; off <= 32; off <<= 1) {
        ssum += __shfl_xor(ssum, off, 64);
        c0 += __shfl_xor(c0, off, 64); c1 += __shfl_xor(c1, off, 64);
        c2 += __shfl_xor(c2, off, 64); c3 += __shfl_xor(c3, off, 64);
        c4 += __shfl_xor(c4, off, 64); c5 += __shfl_xor(c5, off, 64);
        c6 += __shfl_xor(c6, off, 64); c7 += __shfl_xor(c7, off, 64);
    }
    if (eh == 0) {
        float4 bl = ((const float4*)b1)[2 * cq];
        float4 bh = ((const float4*)b1)[2 * cq + 1];
        float inv = frcp(ssum);
        float v0 = c0 * inv + bl.x, v1 = c1 * inv + bl.y;
        float v2 = c2 * inv + bl.z, v3 = c3 * inv + bl.w;
        float v4 = c4 * inv + bh.x, v5 = c5 * inv + bh.y;
        float v6 = c6 * inv + bh.z, v7 = c7 * inv + bh.w;
        v0 = (v0 > 0.f) ? v0 : (fexp(v0) - 1.f);   // ELU
        v1 = (v1 > 0.f) ? v1 : (fexp(v1) - 1.f);
        v2 = (v2 > 0.f) ? v2 : (fexp(v2) - 1.f);
        v3 = (v3 > 0.f) ? v3 : (fexp(v3) - 1.f);
        v4 = (v4 > 0.f) ? v4 : (fexp(v4) - 1.f);
        v5 = (v5 > 0.f) ? v5 : (fexp(v5) - 1.f);
        v6 = (v6 > 0.f) ? v6 : (fexp(v6) - 1.f);
        v7 = (v7 > 0.f) ? v7 : (fexp(v7) - 1.f);
        __half2 p0 = __floats2half2_rn(v0, v1);
        __half2 p1 = __floats2half2_rn(v2, v3);
        __half2 p2 = __floats2half2_rn(v4, v5);
        __half2 p3 = __floats2half2_rn(v6, v7);
        uint4 pk;
        pk.x = *(unsigned*)&p0; pk.y = *(unsigned*)&p1;
        pk.z = *(unsigned*)&p2; pk.w = *(unsigned*)&p3;
        *(uint4*)(hout + (size_t)d * 64 + 8 * cq) = pk;
    }
}

// ------- layer 2 node GEMM via MFMA (h2p fp16, PACKED 40-col/80B rows) ----------
__global__ __launch_bounds__(256) void k_gemm2(
    const __half* __restrict__ hout, const _Float16* __restrict__ Bf2,
    const float* __restrict__ a_src2, const float* __restrict__ a_dst2,
    __half* __restrict__ h2p, float* __restrict__ al2s, float* __restrict__ al2d) {
    int wave = threadIdx.x >> 6, lane = threadIdx.x & 63;
    int row0 = blockIdx.x * 64 + wave * 16;
    if (row0 >= NN) return;
    int g = lane >> 4, li = lane & 15;
    int myrow = row0 + li;
    half8 B[6];
    const half8* bp = (const half8*)Bf2;
    #pragma unroll
    for (int i = 0; i < 6; i++) B[i] = bp[i * 64 + lane];
    floatx4 acc[3] = {{0,0,0,0},{0,0,0,0},{0,0,0,0}};
    #pragma unroll
    for (int kk = 0; kk < 2; kk++) {
        int k0 = kk * 32 + g * 8;
        half8 av = *(const half8*)(hout + (size_t)myrow * 64 + k0);
        #pragma unroll
        for (int ct = 0; ct < 3; ct++)
            acc[ct] = __builtin_amdgcn_mfma_f32_16x16x32_f16(av, B[kk * 3 + ct], acc[ct], 0, 0, 0);
    }
    float ts[4] = {0.f, 0.f, 0.f, 0.f}, td[4] = {0.f, 0.f, 0.f, 0.f};
    #pragma unroll
    for (int ct = 0; ct < 3; ct++) {
        int col = ct * 16 + li;
        bool ok = (col < 40);
        float asv = ok ? a_src2[col] : 0.f;
        float adv = ok ? a_dst2[col] : 0.f;
        #pragma unroll
        for (int r = 0; r < 4; r++) {
            ts[r] += acc[ct][r] * asv;
            td[r] += acc[ct][r] * adv;
            if (ok) h2p[(size_t)(row0 + 4 * g + r) * 40 + col] = __float2half(acc[ct][r]);
        }
    }
    #pragma unroll
    for (int off = 1; off <= 8; off <<= 1)
        #pragma unroll
        for (int r = 0; r < 4; r++) {
            ts[r] += __shfl_xor(ts[r], off, 64);
            td[r] += __shfl_xor(td[r], off, 64);
        }
    if (li == 0) {
        #pragma unroll
        for (int r = 0; r < 4; r++) {
            int row = row0 + 4 * g + r;
            al2s[row] = ts[r] * LOG2E;   // pre-scaled for exp2
            al2d[row] = td[r] * LOG2E;
        }
    }
}

// ------- layer 2 aggregation + log_softmax: 6-slot batch prefetch ---------------
__global__ __launch_bounds__(256) void k_agg2(
    const int2* __restrict__ rowseg, const int* __restrict__ srcs,
    const float* __restrict__ al2s, const float* __restrict__ al2d,
    const __half* __restrict__ h2p, const float* __restrict__ b2,
    float* __restrict__ out) {
    int wave = threadIdx.x >> 6;
    int lane = threadIdx.x & 63;
    int d = blockIdx.x * 4 + wave;
    if (d >= NN) return;
    int eh = lane >> 3;          // edge slot 0..7
    int cq = lane & 7;           // col-octet: cols 8cq..8cq+7; valid iff cq<5
    bool act = (cq < 5);
    int cqc = act ? cq : 4;      // clamped for in-bounds loads (cq>=5 lanes unused)
    unsigned cq16 = (unsigned)cqc << 4;
    const char* H = (const char*)h2p;
    float adst = al2d[d];
    int2 seg = rowseg[d];
    int jb = seg.x, je = seg.y;
    int niter = (je - jb) >> 3;
    int idx[PF];
    #pragma unroll
    for (int k = 0; k < PF; k++) {
        int jj = min(jb + 8 * k, je - 8);
        idx[k] = srcs[jj + eh];
    }
    float alv[PF]; uint4 qv[PF];
    #pragma unroll
    for (int k = 0; k < PF; k++) {
        alv[k] = al2s[idx[k]];
        qv[k]  = *(const uint4*)(H + ((unsigned)idx[k] * 80u + cq16));
    }
    float c0 = 0.f, c1 = 0.f, c2 = 0.f, c3 = 0.f;
    float c4 = 0.f, c5 = 0.f, c6 = 0.f, c7 = 0.f, ssum = 0.f;
    #pragma unroll
    for (int k = 0; k < PF; k++) {
        if (k >= niter) break;               // wave-uniform
        float e = alv[k] + adst;             // pre-scaled by log2e
        float p = fexp2(fmaxf(e, 0.2f * e));
        float2 f0 = __half22float2(*(__half2*)&qv[k].x);
        float2 f1 = __half22float2(*(__half2*)&qv[k].y);
        float2 f2 = __half22float2(*(__half2*)&qv[k].z);
        float2 f3 = __half22float2(*(__half2*)&qv[k].w);
        ssum += p;
        c0 += p * f0.x; c1 += p * f0.y;
        c2 += p * f1.x; c3 += p * f1.y;
        c4 += p * f2.x; c5 += p * f2.y;
        c6 += p * f3.x; c7 += p * f3.y;
    }
    for (int j = jb + 8 * PF; j < je; j += 8) {   // rare tail
        int sn = srcs[j + eh];
        float al = al2s[sn];
        uint4 q = *(const uint4*)(H + ((unsigned)sn * 80u + cq16));
        float e = al + adst;
        float p = fexp2(fmaxf(e, 0.2f * e));
        float2 f0 = __half22float2(*(__half2*)&q.x);
        float2 f1 = __half22float2(*(__half2*)&q.y);
        float2 f2 = __half22float2(*(__half2*)&q.z);
        float2 f3 = __half22float2(*(__half2*)&q.w);
        ssum += p;
        c0 += p * f0.x; c1 += p * f0.y;
        c2 += p * f1.x; c3 += p * f1.y;
        c4 += p * f2.x; c5 += p * f2.y;
        c6 += p * f3.x; c7 += p * f3.y;
    }
    #pragma unroll
    for (int off = 8; off <= 32; off <<= 1) {
        ssum += __shfl_xor(ssum, off, 64);
        c0 += __shfl_xor(c0, off, 64); c1 += __shfl_xor(c1, off, 64);
        c2 += __shfl_xor(c2, off, 64); c3 += __shfl_xor(c3, off, 64);
        c4 += __shfl_xor(c4, off, 64); c5 += __shfl_xor(c5, off, 64);
        c6 += __shfl_xor(c6, off, 64); c7 += __shfl_xor(c7, off, 64);
    }
    float inv = frcp(ssum);
    float4 bl = ((const float4*)b2)[2 * cqc];
    float4 bh = ((const float4*)b2)[2 * cqc + 1];
    float o0 = c0 * inv + bl.x, o1 = c1 * inv + bl.y;
    float o2 = c2 * inv + bl.z, o3 = c3 * inv + bl.w;
    float o4 = c4 * inv + bh.x, o5 = c5 * inv + bh.y;
    float o6 = c6 * inv + bh.z, o7 = c7 * inv + bh.w;
    float mo = act ? fmaxf(fmaxf(fmaxf(o0, o1), fmaxf(o2, o3)),
                           fmaxf(fmaxf(o4, o5), fmaxf(o6, o7))) : -3.0e38f;
    #pragma unroll
    for (int off = 1; off <= 4; off <<= 1) mo = fmaxf(mo, __shfl_xor(mo, off, 64));
    float te = act ? (fexp(o0 - mo) + fexp(o1 - mo) + fexp(o2 - mo) + fexp(o3 - mo) +
                      fexp(o4 - mo) + fexp(o5 - mo) + fexp(o6 - mo) + fexp(o7 - mo)) : 0.f;
    #pragma unroll
    for (int off = 1; off <= 4; off <<= 1) te += __shfl_xor(te, off, 64);
    float ls = mo + flog(te);
    if (act && eh == 0) {
        float4 lo = make_float4(o0 - ls, o1 - ls, o2 - ls, o3 - ls);
        float4 hi = make_float4(o4 - ls, o5 - ls, o6 - ls, o7 - ls);
        *(float4*)(out + (size_t)d * 40 + 8 * cq) = lo;
        *(float4*)(out + (size_t)d * 40 + 8 * cq + 4) = hi;
    }
}

extern "C" void kernel_launch(void* const* d_in, const int* in_sizes, int n_in,
                              void* d_out, int out_size, void* d_ws, size_t ws_size,
                              hipStream_t stream) {
    (void)in_sizes; (void)n_in; (void)out_size; (void)ws_size;
    const float* x    = (const float*)d_in[0];
    const float* topo = (const float*)d_in[1];
    const int*   ei   = (const int*)d_in[2];
    const float* W1   = (const float*)d_in[3];
    const float* as1  = (const float*)d_in[4];
    const float* ad1  = (const float*)d_in[5];
    const float* b1   = (const float*)d_in[6];
    const float* W2   = (const float*)d_in[7];
    const float* as2  = (const float*)d_in[8];
    const float* ad2  = (const float*)d_in[9];
    const float* b2   = (const float*)d_in[10];
    float* out = (float*)d_out;

    char* ws = (char*)d_ws;
    size_t off = 0;
    auto alloc = [&](size_t bytes) {
        void* p = ws + off;
        off += (bytes + 255) / 256 * 256;
        return p;
    };
    int2*          rowseg     = (int2*)alloc((size_t)NN * 8);
    int*           cursor     = (int*)alloc(NBUCK * 4);
    unsigned*      bucketData = (unsigned*)alloc((size_t)NBUCK * CAP * 4);
    int*           srcs       = (int*)alloc((size_t)SRCS_MAX * 4);
    float*         alsrc1     = (float*)alloc((size_t)(NN + 1) * 8 * 4);
    float*         aldst1     = (float*)alloc((size_t)NN * 8 * 4);
    float*         al2s       = (float*)alloc((NN + 1) * 4);
    float*         al2d       = (float*)alloc(NN * 4);
    _Float16*      Bf1        = (_Float16*)alloc(4 * 4 * 64 * 8 * 2);
    _Float16*      Bf2        = (_Float16*)alloc(2 * 3 * 64 * 8 * 2);
    unsigned char* h1         = (unsigned char*)alloc((size_t)(NN + 1) * 64);
    __half*        hout       = (__half*)alloc((size_t)NN * 64 * 2);
    __half*        h2p        = (__half*)alloc((size_t)(NN + 1) * 40 * 2);

    k_prep    <<<7,         256,  0, stream>>>(W1, W2, Bf1, Bf2, cursor, alsrc1, al2s, h1, h2p);
    k_fusedAG <<<NBA + NGB, 256,  0, stream>>>(ei, cursor, bucketData,
                                               x, topo, Bf1, as1, ad1, h1, alsrc1, aldst1);
    k_bucketB <<<NBUCK,     1024, 0, stream>>>(bucketData, cursor, rowseg, srcs);
    k_agg1    <<<(NN + 3) / 4, 256, 0, stream>>>(rowseg, srcs, alsrc1, aldst1, h1, b1, hout);
    k_gemm2   <<<782,       256,  0, stream>>>(hout, Bf2, as2, ad2, h2p, al2s, al2d);
    k_agg2    <<<(NN + 3) / 4, 256, 0, stream>>>(rowseg, srcs, al2s, al2d, h2p, b2, out);
}